// Round 5
// baseline (355.854 us; speedup 1.0000x reference)
//
#include <hip/hip_runtime.h>
#include <hip/hip_bf16.h>

typedef __attribute__((ext_vector_type(8))) short bf16x8;
typedef __attribute__((ext_vector_type(4))) float f32x4;

#define BUCKET_CAP 2048   // slots per 64-node dst bucket (mean ~1024, sigma ~32)

__device__ inline unsigned short f2bf(float f) {
    unsigned u = __float_as_uint(f);
    return (unsigned short)((u + 0x7fffu + ((u >> 16) & 1u)) >> 16);
}
__device__ inline unsigned pack2(float a, float b) {
    return (unsigned)f2bf(a) | ((unsigned)f2bf(b) << 16);
}
__device__ inline float blo(unsigned u) { return __uint_as_float(u << 16); }
__device__ inline float bhi(unsigned u) { return __uint_as_float(u & 0xffff0000u); }

// ---------------- casts ----------------
__global__ void cast_f32_bf16(const float4* __restrict__ in, uint4* __restrict__ out, int n8) {
    int i = blockIdx.x * blockDim.x + threadIdx.x;
    if (i >= n8) return;
    float4 a = in[i * 2], b = in[i * 2 + 1];
    uint4 o;
    o.x = pack2(a.x, a.y); o.y = pack2(a.z, a.w);
    o.z = pack2(b.x, b.y); o.w = pack2(b.z, b.w);
    out[i] = o;
}

// W[K][Nc] fp32 -> Wt[Nc][K] bf16
__global__ void cast_wt(const float* __restrict__ W, unsigned short* __restrict__ Wt,
                        int K, int Nc) {
    int idx = blockIdx.x * blockDim.x + threadIdx.x;
    if (idx >= K * Nc) return;
    int n = idx / K;
    int k = idx - n * K;
    Wt[idx] = f2bf(W[k * Nc + n]);
}

// ---------------- bucketed CSR build ----------------
// Pass A: append (src | dst_local<<16) into per-bucket region. Positions within a
// bucket are sequential across concurrent waves -> L2 line-dense writes (~1x amp).
// NOTE: packs src in 16 bits — requires N <= 65536 (here N = 50000).
__global__ void bucket_scatter(const int* __restrict__ ei, int* __restrict__ bcnt,
                               unsigned* __restrict__ pairs, int E) {
    int e = blockIdx.x * blockDim.x + threadIdx.x;
    if (e >= E) return;
    int s = ei[e], d = ei[E + e];
    int b = d >> 6;
    int pos = atomicAdd(&bcnt[b], 1);
    if (pos < BUCKET_CAP) pairs[b * BUCKET_CAP + pos] = (unsigned)s | ((unsigned)(d & 63) << 16);
}

// Exclusive scan of bucket counts (nb <= 1024), one block; also offs[N] = total.
__global__ void scan_buckets(const int* __restrict__ bcnt, int* __restrict__ bbase,
                             int* __restrict__ offs, int nb, int N) {
    __shared__ int lds[1024];
    int i = threadIdx.x;
    int v = (i < nb) ? min(bcnt[i], BUCKET_CAP) : 0;
    lds[i] = v;
    __syncthreads();
    for (int off = 1; off < 1024; off <<= 1) {
        int t = (i >= off) ? lds[i - off] : 0;
        __syncthreads();
        lds[i] += t;
        __syncthreads();
    }
    if (i < nb) bbase[i] = lds[i] - v;
    if (i == nb - 1) offs[N] = lds[i];
}

// Pass B: one workgroup per bucket. LDS 64-bin hist -> wave scan -> LDS reorder ->
// coalesced srcs runs + direct offs writes.
__global__ __launch_bounds__(256) void bucket_build(const unsigned* __restrict__ pairs,
                                                    const int* __restrict__ bcnt,
                                                    const int* __restrict__ bbase,
                                                    int* __restrict__ offs,
                                                    int* __restrict__ srcs, int N) {
    __shared__ unsigned spk[BUCKET_CAP];
    __shared__ int stage[BUCKET_CAP];
    __shared__ int cnt64[64], cur64[64];
    int b = blockIdx.x;
    int cnt = min(bcnt[b], BUCKET_CAP);
    int base = bbase[b];
    int t = threadIdx.x;
    if (t < 64) cnt64[t] = 0;
    __syncthreads();
    for (int i = t; i < cnt; i += 256) {
        unsigned p = pairs[b * BUCKET_CAP + i];
        spk[i] = p;
        atomicAdd(&cnt64[p >> 16], 1);
    }
    __syncthreads();
    if (t < 64) {  // first wave: inclusive shuffle-scan over 64 bins
        int v = cnt64[t];
        int x = v;
#pragma unroll
        for (int o = 1; o < 64; o <<= 1) {
            int y = __shfl_up(x, o);
            if (t >= o) x += y;
        }
        int excl = x - v;
        cur64[t] = excl;
        int node = b * 64 + t;
        if (node < N) offs[node] = base + excl;
    }
    __syncthreads();
    for (int i = t; i < cnt; i += 256) {
        unsigned p = spk[i];
        int pos = atomicAdd(&cur64[p >> 16], 1);
        stage[pos] = (int)(p & 0xffffu);
    }
    __syncthreads();
    for (int i = t; i < cnt; i += 256) srcs[base + i] = stage[i];
}

// ---------------- gather aggregation, bf16 in / bf16 out ----------------
__global__ void gather_agg_bf16(const uint4* __restrict__ xb, const int* __restrict__ offs,
                                const int* __restrict__ srcs, uint4* __restrict__ agg,
                                int N, int C) {
    int gid = blockIdx.x * blockDim.x + threadIdx.x;
    int n = gid / C;
    if (n >= N) return;
    int q = gid - n * C;
    int s0 = offs[n], s1 = offs[n + 1];
    float a0 = 0, a1 = 0, a2 = 0, a3 = 0, a4 = 0, a5 = 0, a6 = 0, a7 = 0;
    for (int e = s0; e < s1; ++e) {
        uint4 v = xb[(long)srcs[e] * C + q];
        a0 += blo(v.x); a1 += bhi(v.x);
        a2 += blo(v.y); a3 += bhi(v.y);
        a4 += blo(v.z); a5 += bhi(v.z);
        a6 += blo(v.w); a7 += bhi(v.w);
    }
    uint4 o;
    o.x = pack2(a0, a1); o.y = pack2(a2, a3);
    o.z = pack2(a4, a5); o.w = pack2(a6, a7);
    agg[(long)n * C + q] = o;
}

// ---------------- MFMA GEMMs ----------------
__global__ void mfma_gemm1_relu(const unsigned short* __restrict__ A,
                                const unsigned short* __restrict__ Bt,
                                const float* __restrict__ bias,
                                unsigned short* __restrict__ H, int Mtiles) {
    int wave = blockIdx.x * 4 + (threadIdx.x >> 6);
    if (wave >= Mtiles) return;
    int lane = threadIdx.x & 63;
    int l15 = lane & 15, quad = lane >> 4;
    const int K = 96;
    long arow = (long)(wave * 16 + l15) * K + quad * 8;
    f32x4 acc[4] = {{0,0,0,0},{0,0,0,0},{0,0,0,0},{0,0,0,0}};
#pragma unroll
    for (int t = 0; t < 3; ++t) {
        bf16x8 af = *(const bf16x8*)(A + arow + t * 32);
#pragma unroll
        for (int nt = 0; nt < 4; ++nt) {
            bf16x8 bfr = *(const bf16x8*)(Bt + (long)(nt * 16 + l15) * K + t * 32 + quad * 8);
            acc[nt] = __builtin_amdgcn_mfma_f32_16x16x32_bf16(af, bfr, acc[nt], 0, 0, 0);
        }
    }
    int mbase = wave * 16 + quad * 4;  // C/D: row = quad*4 + reg, col = l15
#pragma unroll
    for (int nt = 0; nt < 4; ++nt) {
        int col = nt * 16 + l15;
        float bb = bias[col];
#pragma unroll
        for (int r = 0; r < 4; ++r) {
            float v = fmaxf(acc[nt][r] + bb, 0.f);
            H[(long)(mbase + r) * 64 + col] = f2bf(v);
        }
    }
}

__global__ void mfma_gemm2_lsm(const unsigned short* __restrict__ A,
                               const unsigned short* __restrict__ Bt,
                               const float* __restrict__ bias,
                               float* __restrict__ out, int Mtiles) {
    int wave = blockIdx.x * 4 + (threadIdx.x >> 6);
    if (wave >= Mtiles) return;
    int lane = threadIdx.x & 63;
    int l15 = lane & 15, quad = lane >> 4;
    const int K = 64;
    long arow = (long)(wave * 16 + l15) * K + quad * 8;
    f32x4 acc[2] = {{0,0,0,0},{0,0,0,0}};
#pragma unroll
    for (int t = 0; t < 2; ++t) {
        bf16x8 af = *(const bf16x8*)(A + arow + t * 32);
#pragma unroll
        for (int nt = 0; nt < 2; ++nt) {
            bf16x8 bfr = *(const bf16x8*)(Bt + (long)(nt * 16 + l15) * K + t * 32 + quad * 8);
            acc[nt] = __builtin_amdgcn_mfma_f32_16x16x32_bf16(af, bfr, acc[nt], 0, 0, 0);
        }
    }
    float b0 = bias[l15], b16 = bias[16 + l15];
    int mbase = wave * 16 + quad * 4;
#pragma unroll
    for (int r = 0; r < 4; ++r) {
        float v0 = acc[0][r] + b0;
        float v1 = acc[1][r] + b16;
        float m = fmaxf(v0, v1);
#pragma unroll
        for (int o = 1; o < 16; o <<= 1) m = fmaxf(m, __shfl_xor(m, o));
        float s = __expf(v0 - m) + __expf(v1 - m);
#pragma unroll
        for (int o = 1; o < 16; o <<= 1) s += __shfl_xor(s, o);
        float ls = __logf(s);
        long rb = (long)(mbase + r) * 32;
        out[rb + l15] = v0 - m - ls;
        out[rb + 16 + l15] = v1 - m - ls;
    }
}

extern "C" void kernel_launch(void* const* d_in, const int* in_sizes, int n_in,
                              void* d_out, int out_size, void* d_ws, size_t ws_size,
                              hipStream_t stream) {
    const float* x  = (const float*)d_in[0];      // [N,96]
    const int*   ei = (const int*)d_in[1];        // [2,E] (int64 -> int32 on device)
    const float* W1 = (const float*)d_in[2];      // [96,64]
    const float* b1 = (const float*)d_in[3];      // [64]
    const float* W2 = (const float*)d_in[4];      // [64,32]
    const float* b2 = (const float*)d_in[5];      // [32]
    float* out = (float*)d_out;                   // [N,32]

    const int N = in_sizes[0] / 96;
    const int E = in_sizes[1] / 2;
    const int nb = (N + 63) / 64;                 // 782 buckets

    // ws layout (16B-aligned slabs)
    char* p = (char*)d_ws;
    unsigned short* aggb = (unsigned short*)p;    p += (size_t)N * 96 * 2;          // agg1/agg2
    unsigned short* hb   = (unsigned short*)p;    p += (size_t)N * 64 * 2;          // h bf16
    unsigned short* xb   = (unsigned short*)p;    p += (size_t)N * 96 * 2;          // x bf16
    unsigned short* w1t  = (unsigned short*)p;    p += 96 * 64 * 2;
    unsigned short* w2t  = (unsigned short*)p;    p += 64 * 32 * 2 + 64;            // pad to 16B
    int* offs   = (int*)p;                        p += (size_t)(N + 1) * 4 + 60;    // keep alignment
    int* bcnt   = (int*)p;                        p += (size_t)nb * 4;
    int* bbase  = (int*)p;                        p += (size_t)nb * 4 + 56;
    unsigned* pairs = (unsigned*)p;               p += (size_t)nb * BUCKET_CAP * 4; // 6.4 MB
    int* srcs   = (int*)p;                        p += (size_t)E * 4;

    // casts (independent of CSR build)
    {
        int n8 = N * 96 / 8;
        cast_f32_bf16<<<(n8 + 255) / 256, 256, 0, stream>>>((const float4*)x, (uint4*)xb, n8);
        cast_wt<<<(96 * 64 + 255) / 256, 256, 0, stream>>>(W1, w1t, 96, 64);
        cast_wt<<<(64 * 32 + 255) / 256, 256, 0, stream>>>(W2, w2t, 64, 32);
    }

    // bucketed CSR build by dst
    hipMemsetAsync(bcnt, 0, (size_t)nb * sizeof(int), stream);
    bucket_scatter<<<(E + 255) / 256, 256, 0, stream>>>(ei, bcnt, pairs, E);
    scan_buckets<<<1, 1024, 0, stream>>>(bcnt, bbase, offs, nb, N);
    bucket_build<<<nb, 256, 0, stream>>>(pairs, bcnt, bbase, offs, srcs, N);

    const int Mtiles = N / 16;  // 50000/16 = 3125 exactly

    // Layer 1
    {
        long t = (long)N * 12;
        gather_agg_bf16<<<(int)((t + 255) / 256), 256, 0, stream>>>(
            (const uint4*)xb, offs, srcs, (uint4*)aggb, N, 12);
    }
    mfma_gemm1_relu<<<(Mtiles + 3) / 4, 256, 0, stream>>>(aggb, w1t, b1, hb, Mtiles);

    // Layer 2 (agg2 reuses aggb slot)
    {
        long t = (long)N * 8;
        gather_agg_bf16<<<(int)((t + 255) / 256), 256, 0, stream>>>(
            (const uint4*)hb, offs, srcs, (uint4*)aggb, N, 8);
    }
    mfma_gemm2_lsm<<<(Mtiles + 3) / 4, 256, 0, stream>>>(aggb, w2t, b2, out, Mtiles);
}

// Round 6
// 212.090 us; speedup vs baseline: 1.6778x; 1.6778x over previous
//
#include <hip/hip_runtime.h>
#include <hip/hip_bf16.h>

typedef __attribute__((ext_vector_type(8))) short bf16x8;
typedef __attribute__((ext_vector_type(4))) float f32x4;

#define NBLK 128          // blocks for hist/place passes
#define NBINS_PAD 800     // LDS bin array (nb = 782 used)
#define BCAP 2048         // bucket_build LDS capacity (mean 1024, sigma 32)

__device__ inline unsigned short f2bf(float f) {
    unsigned u = __float_as_uint(f);
    return (unsigned short)((u + 0x7fffu + ((u >> 16) & 1u)) >> 16);
}
__device__ inline unsigned pack2(float a, float b) {
    return (unsigned)f2bf(a) | ((unsigned)f2bf(b) << 16);
}
__device__ inline float blo(unsigned u) { return __uint_as_float(u << 16); }
__device__ inline float bhi(unsigned u) { return __uint_as_float(u & 0xffff0000u); }

// ---------------- casts ----------------
__global__ void cast_f32_bf16(const float4* __restrict__ in, uint4* __restrict__ out, int n8) {
    int i = blockIdx.x * blockDim.x + threadIdx.x;
    if (i >= n8) return;
    float4 a = in[i * 2], b = in[i * 2 + 1];
    uint4 o;
    o.x = pack2(a.x, a.y); o.y = pack2(a.z, a.w);
    o.z = pack2(b.x, b.y); o.w = pack2(b.z, b.w);
    out[i] = o;
}

__global__ void cast_wt(const float* __restrict__ W, unsigned short* __restrict__ Wt,
                        int K, int Nc) {
    int idx = blockIdx.x * blockDim.x + threadIdx.x;
    if (idx >= K * Nc) return;
    int n = idx / K;
    int k = idx - n * K;
    Wt[idx] = f2bf(W[k * Nc + n]);
}

// ---------------- atomic-free bucketed CSR build ----------------
// Pass 1: per-block LDS histogram over coarse buckets (dst>>6). counts[b][j].
__global__ __launch_bounds__(256) void blk_hist(const int* __restrict__ ei,
                                                int* __restrict__ counts,
                                                int E, int chunk, int nb) {
    __shared__ int hist[NBINS_PAD];
    int b = blockIdx.x, t = threadIdx.x;
    for (int i = t; i < NBINS_PAD; i += 256) hist[i] = 0;
    __syncthreads();
    int e0 = b * chunk;
    int n = E - e0; if (n > chunk) n = chunk; if (n < 0) n = 0;
    for (int i = t; i < n; i += 256) atomicAdd(&hist[ei[E + e0 + i] >> 6], 1);
    __syncthreads();
    for (int j = t; j < nb; j += 256) counts[b * nb + j] = hist[j];
}

// Pass 2: per-bucket exclusive scan across blocks (in place); totals to btot.
__global__ void colscan(int* __restrict__ counts, int* __restrict__ btot, int nblk, int nb) {
    int j = blockIdx.x * blockDim.x + threadIdx.x;
    if (j >= nb) return;
    int run = 0;
    for (int b = 0; b < nblk; ++b) {
        int c = counts[b * nb + j];
        counts[b * nb + j] = run;
        run += c;
    }
    btot[j] = run;
}

// Pass 3: exclusive scan of bucket totals -> bbase[nb+1]; offs[N] = E.
__global__ void scan_buckets(const int* __restrict__ btot, int* __restrict__ bbase,
                             int* __restrict__ offs, int nb, int N, int E) {
    __shared__ int lds[1024];
    int i = threadIdx.x;
    int v = (i < nb) ? btot[i] : 0;
    lds[i] = v;
    __syncthreads();
    for (int off = 1; off < 1024; off <<= 1) {
        int t = (i >= off) ? lds[i - off] : 0;
        __syncthreads();
        lds[i] += t;
        __syncthreads();
    }
    if (i < nb) bbase[i] = lds[i] - v;
    if (i == 0) { bbase[nb] = E; offs[N] = E; }
}

// Pass 4: place packed pairs at exact global positions (LDS atomics only).
__global__ __launch_bounds__(256) void blk_place(const int* __restrict__ ei,
                                                 const int* __restrict__ counts,
                                                 const int* __restrict__ bbase,
                                                 unsigned* __restrict__ pairs,
                                                 int E, int chunk, int nb) {
    __shared__ int cur[NBINS_PAD];
    int b = blockIdx.x, t = threadIdx.x;
    for (int j = t; j < nb; j += 256) cur[j] = bbase[j] + counts[b * nb + j];
    __syncthreads();
    int e0 = b * chunk;
    int n = E - e0; if (n > chunk) n = chunk; if (n < 0) n = 0;
    for (int i = t; i < n; i += 256) {
        int s = ei[e0 + i], d = ei[E + e0 + i];
        int pos = atomicAdd(&cur[d >> 6], 1);
        pairs[pos] = (unsigned)s | ((unsigned)(d & 63) << 16);
    }
}

// Pass 5: one workgroup per bucket: 64-bin LDS sort -> coalesced srcs + offs.
__global__ __launch_bounds__(256) void bucket_build(const unsigned* __restrict__ pairs,
                                                    const int* __restrict__ bbase,
                                                    int* __restrict__ offs,
                                                    int* __restrict__ srcs, int N) {
    __shared__ unsigned spk[BCAP];
    __shared__ int stage[BCAP];
    __shared__ int cnt64[64], cur64[64];
    int b = blockIdx.x, t = threadIdx.x;
    int base = bbase[b];
    int cnt = bbase[b + 1] - base; if (cnt > BCAP) cnt = BCAP;
    if (t < 64) cnt64[t] = 0;
    __syncthreads();
    for (int i = t; i < cnt; i += 256) {
        unsigned p = pairs[base + i];
        spk[i] = p;
        atomicAdd(&cnt64[(p >> 16) & 63], 1);
    }
    __syncthreads();
    if (t < 64) {  // wave 0: inclusive shuffle-scan over 64 bins
        int v = cnt64[t], x = v;
#pragma unroll
        for (int o = 1; o < 64; o <<= 1) {
            int y = __shfl_up(x, o);
            if (t >= o) x += y;
        }
        int excl = x - v;
        cur64[t] = excl;
        int node = b * 64 + t;
        if (node < N) offs[node] = base + excl;
    }
    __syncthreads();
    for (int i = t; i < cnt; i += 256) {
        unsigned p = spk[i];
        int pos = atomicAdd(&cur64[(p >> 16) & 63], 1);
        stage[pos] = (int)(p & 0xffffu);
    }
    __syncthreads();
    for (int i = t; i < cnt; i += 256) srcs[base + i] = stage[i];
}

// ---------------- gather aggregation, bf16 in / bf16 out ----------------
__global__ void gather_agg_bf16(const uint4* __restrict__ xb, const int* __restrict__ offs,
                                const int* __restrict__ srcs, uint4* __restrict__ agg,
                                int N, int C) {
    int gid = blockIdx.x * blockDim.x + threadIdx.x;
    int n = gid / C;
    if (n >= N) return;
    int q = gid - n * C;
    int s0 = offs[n], s1 = offs[n + 1];
    float a0 = 0, a1 = 0, a2 = 0, a3 = 0, a4 = 0, a5 = 0, a6 = 0, a7 = 0;
    for (int e = s0; e < s1; ++e) {
        uint4 v = xb[(long)srcs[e] * C + q];
        a0 += blo(v.x); a1 += bhi(v.x);
        a2 += blo(v.y); a3 += bhi(v.y);
        a4 += blo(v.z); a5 += bhi(v.z);
        a6 += blo(v.w); a7 += bhi(v.w);
    }
    uint4 o;
    o.x = pack2(a0, a1); o.y = pack2(a2, a3);
    o.z = pack2(a4, a5); o.w = pack2(a6, a7);
    agg[(long)n * C + q] = o;
}

// ---------------- MFMA GEMMs ----------------
__global__ void mfma_gemm1_relu(const unsigned short* __restrict__ A,
                                const unsigned short* __restrict__ Bt,
                                const float* __restrict__ bias,
                                unsigned short* __restrict__ H, int Mtiles) {
    int wave = blockIdx.x * 4 + (threadIdx.x >> 6);
    if (wave >= Mtiles) return;
    int lane = threadIdx.x & 63;
    int l15 = lane & 15, quad = lane >> 4;
    const int K = 96;
    long arow = (long)(wave * 16 + l15) * K + quad * 8;
    f32x4 acc[4] = {{0,0,0,0},{0,0,0,0},{0,0,0,0},{0,0,0,0}};
#pragma unroll
    for (int t = 0; t < 3; ++t) {
        bf16x8 af = *(const bf16x8*)(A + arow + t * 32);
#pragma unroll
        for (int nt = 0; nt < 4; ++nt) {
            bf16x8 bfr = *(const bf16x8*)(Bt + (long)(nt * 16 + l15) * K + t * 32 + quad * 8);
            acc[nt] = __builtin_amdgcn_mfma_f32_16x16x32_bf16(af, bfr, acc[nt], 0, 0, 0);
        }
    }
    int mbase = wave * 16 + quad * 4;  // C/D: row = quad*4 + reg, col = l15
#pragma unroll
    for (int nt = 0; nt < 4; ++nt) {
        int col = nt * 16 + l15;
        float bb = bias[col];
#pragma unroll
        for (int r = 0; r < 4; ++r) {
            float v = fmaxf(acc[nt][r] + bb, 0.f);
            H[(long)(mbase + r) * 64 + col] = f2bf(v);
        }
    }
}

__global__ void mfma_gemm2_lsm(const unsigned short* __restrict__ A,
                               const unsigned short* __restrict__ Bt,
                               const float* __restrict__ bias,
                               float* __restrict__ out, int Mtiles) {
    int wave = blockIdx.x * 4 + (threadIdx.x >> 6);
    if (wave >= Mtiles) return;
    int lane = threadIdx.x & 63;
    int l15 = lane & 15, quad = lane >> 4;
    const int K = 64;
    long arow = (long)(wave * 16 + l15) * K + quad * 8;
    f32x4 acc[2] = {{0,0,0,0},{0,0,0,0}};
#pragma unroll
    for (int t = 0; t < 2; ++t) {
        bf16x8 af = *(const bf16x8*)(A + arow + t * 32);
#pragma unroll
        for (int nt = 0; nt < 2; ++nt) {
            bf16x8 bfr = *(const bf16x8*)(Bt + (long)(nt * 16 + l15) * K + t * 32 + quad * 8);
            acc[nt] = __builtin_amdgcn_mfma_f32_16x16x32_bf16(af, bfr, acc[nt], 0, 0, 0);
        }
    }
    float b0 = bias[l15], b16 = bias[16 + l15];
    int mbase = wave * 16 + quad * 4;
#pragma unroll
    for (int r = 0; r < 4; ++r) {
        float v0 = acc[0][r] + b0;
        float v1 = acc[1][r] + b16;
        float m = fmaxf(v0, v1);
#pragma unroll
        for (int o = 1; o < 16; o <<= 1) m = fmaxf(m, __shfl_xor(m, o));
        float s = __expf(v0 - m) + __expf(v1 - m);
#pragma unroll
        for (int o = 1; o < 16; o <<= 1) s += __shfl_xor(s, o);
        float ls = __logf(s);
        long rb = (long)(mbase + r) * 32;
        out[rb + l15] = v0 - m - ls;
        out[rb + 16 + l15] = v1 - m - ls;
    }
}

extern "C" void kernel_launch(void* const* d_in, const int* in_sizes, int n_in,
                              void* d_out, int out_size, void* d_ws, size_t ws_size,
                              hipStream_t stream) {
    const float* x  = (const float*)d_in[0];      // [N,96]
    const int*   ei = (const int*)d_in[1];        // [2,E] (int64 -> int32 on device)
    const float* W1 = (const float*)d_in[2];      // [96,64]
    const float* b1 = (const float*)d_in[3];      // [64]
    const float* W2 = (const float*)d_in[4];      // [64,32]
    const float* b2 = (const float*)d_in[5];      // [32]
    float* out = (float*)d_out;                   // [N,32]

    const int N = in_sizes[0] / 96;
    const int E = in_sizes[1] / 2;
    const int nb = (N + 63) / 64;                 // 782 coarse buckets
    const int chunk = (E + NBLK - 1) / NBLK;      // 6250 edges per hist/place block

    // ws layout (16B-aligned slabs)
    char* p = (char*)d_ws;
    unsigned short* aggb = (unsigned short*)p;    p += (size_t)N * 96 * 2;     // agg1/agg2
    unsigned short* hb   = (unsigned short*)p;    p += (size_t)N * 64 * 2;     // h bf16
    unsigned short* xb   = (unsigned short*)p;    p += (size_t)N * 96 * 2;     // x bf16
    unsigned short* w1t  = (unsigned short*)p;    p += 96 * 64 * 2;
    unsigned short* w2t  = (unsigned short*)p;    p += 64 * 32 * 2;
    int* offs   = (int*)p;                        p += ((size_t)(N + 1) * 4 + 12) & ~15ull;
    int* counts = (int*)p;                        p += ((size_t)NBLK * nb * 4 + 12) & ~15ull;
    int* btot   = (int*)p;                        p += ((size_t)nb * 4 + 12) & ~15ull;
    int* bbase  = (int*)p;                        p += ((size_t)(nb + 1) * 4 + 12) & ~15ull;
    unsigned* pairs = (unsigned*)p;               p += (size_t)E * 4;          // dense, 3.2 MB
    int* srcs   = (int*)p;                        p += (size_t)E * 4;

    // casts (independent of CSR build)
    {
        int n8 = N * 96 / 8;
        cast_f32_bf16<<<(n8 + 255) / 256, 256, 0, stream>>>((const float4*)x, (uint4*)xb, n8);
        cast_wt<<<(96 * 64 + 255) / 256, 256, 0, stream>>>(W1, w1t, 96, 64);
        cast_wt<<<(64 * 32 + 255) / 256, 256, 0, stream>>>(W2, w2t, 64, 32);
    }

    // atomic-free bucketed CSR build by dst
    blk_hist<<<NBLK, 256, 0, stream>>>(ei, counts, E, chunk, nb);
    colscan<<<(nb + 255) / 256, 256, 0, stream>>>(counts, btot, NBLK, nb);
    scan_buckets<<<1, 1024, 0, stream>>>(btot, bbase, offs, nb, N, E);
    blk_place<<<NBLK, 256, 0, stream>>>(ei, counts, bbase, pairs, E, chunk, nb);
    bucket_build<<<nb, 256, 0, stream>>>(pairs, bbase, offs, srcs, N);

    const int Mtiles = N / 16;  // 50000/16 = 3125 exactly

    // Layer 1
    {
        long t = (long)N * 12;
        gather_agg_bf16<<<(int)((t + 255) / 256), 256, 0, stream>>>(
            (const uint4*)xb, offs, srcs, (uint4*)aggb, N, 12);
    }
    mfma_gemm1_relu<<<(Mtiles + 3) / 4, 256, 0, stream>>>(aggb, w1t, b1, hb, Mtiles);

    // Layer 2 (agg2 reuses aggb slot)
    {
        long t = (long)N * 8;
        gather_agg_bf16<<<(int)((t + 255) / 256), 256, 0, stream>>>(
            (const uint4*)hb, offs, srcs, (uint4*)aggb, N, 8);
    }
    mfma_gemm2_lsm<<<(Mtiles + 3) / 4, 256, 0, stream>>>(aggb, w2t, b2, out, Mtiles);
}

// Round 7
// 197.890 us; speedup vs baseline: 1.7982x; 1.0718x over previous
//
#include <hip/hip_runtime.h>
#include <hip/hip_bf16.h>

typedef __attribute__((ext_vector_type(8))) short bf16x8;
typedef __attribute__((ext_vector_type(4))) float f32x4;

#define NBLK 128          // blocks for hist/place passes
#define NBINS_PAD 800     // LDS bin array (nb = 782 used)
#define BCAP 2048         // bucket_build LDS capacity (mean 1024, max ~1150)

__device__ inline unsigned short f2bf(float f) {
    unsigned u = __float_as_uint(f);
    return (unsigned short)((u + 0x7fffu + ((u >> 16) & 1u)) >> 16);
}
__device__ inline unsigned pack2(float a, float b) {
    return (unsigned)f2bf(a) | ((unsigned)f2bf(b) << 16);
}
__device__ inline float blo(unsigned u) { return __uint_as_float(u << 16); }
__device__ inline float bhi(unsigned u) { return __uint_as_float(u & 0xffff0000u); }

// ---------------- weight casts (both in one launch) ----------------
// w1t[n][k] = bf16(W1[k][n])  (64x96); w2t[n][k] = bf16(W2[k][n]) (32x64)
__global__ void cast_weights(const float* __restrict__ W1, const float* __restrict__ W2,
                             unsigned short* __restrict__ w1t, unsigned short* __restrict__ w2t) {
    int idx = blockIdx.x * blockDim.x + threadIdx.x;
    if (idx < 96 * 64) {
        int n = idx / 96, k = idx - n * 96;
        w1t[idx] = f2bf(W1[k * 64 + n]);
    } else if (idx < 96 * 64 + 64 * 32) {
        int j = idx - 96 * 64;
        int n = j / 64, k = j - n * 64;
        w2t[j] = f2bf(W2[k * 32 + n]);
    }
}

// ---------------- atomic-free bucketed CSR build ----------------
// Pass 1: per-block LDS histogram; counts stored TRANSPOSED: counts[j*NBLK + b].
__global__ __launch_bounds__(256) void blk_hist(const int* __restrict__ ei,
                                                int* __restrict__ counts,
                                                int E, int chunk, int nb) {
    __shared__ int hist[NBINS_PAD];
    int b = blockIdx.x, t = threadIdx.x;
    for (int i = t; i < NBINS_PAD; i += 256) hist[i] = 0;
    __syncthreads();
    int e0 = b * chunk;
    int n = E - e0; if (n > chunk) n = chunk; if (n < 0) n = 0;
    for (int i = t; i < n; i += 256) atomicAdd(&hist[ei[E + e0 + i] >> 6], 1);
    __syncthreads();
    for (int j = t; j < nb; j += 256) counts[j * NBLK + b] = hist[j];
}

// Pass 2 (fused): per-bucket exclusive scan across blocks (contiguous reads, in place)
// + bucket-level scan -> bbase; offs[N] = E.
__global__ __launch_bounds__(1024) void colscan_scan(int* __restrict__ counts,
                                                     int* __restrict__ bbase,
                                                     int* __restrict__ offs,
                                                     int nb, int N, int E) {
    __shared__ int lds[1024];
    int j = threadIdx.x;
    int run = 0;
    if (j < nb) {
        int* row = counts + (size_t)j * NBLK;
#pragma unroll 4
        for (int b = 0; b < NBLK; ++b) { int c = row[b]; row[b] = run; run += c; }
    }
    lds[j] = (j < nb) ? run : 0;
    __syncthreads();
    for (int off = 1; off < 1024; off <<= 1) {
        int t = (j >= off) ? lds[j - off] : 0;
        __syncthreads();
        lds[j] += t;
        __syncthreads();
    }
    if (j < nb) bbase[j] = lds[j] - run;
    if (j == 0) { bbase[nb] = E; offs[N] = E; }
}

// Pass 3: place packed (src | dst_local<<16) at exact global positions (LDS atomics only).
__global__ __launch_bounds__(256) void blk_place(const int* __restrict__ ei,
                                                 const int* __restrict__ counts,
                                                 const int* __restrict__ bbase,
                                                 unsigned* __restrict__ pairs,
                                                 int E, int chunk, int nb) {
    __shared__ int cur[NBINS_PAD];
    int b = blockIdx.x, t = threadIdx.x;
    for (int j = t; j < nb; j += 256) cur[j] = bbase[j] + counts[j * NBLK + b];
    __syncthreads();
    int e0 = b * chunk;
    int n = E - e0; if (n > chunk) n = chunk; if (n < 0) n = 0;
    for (int i = t; i < n; i += 256) {
        int s = ei[e0 + i], d = ei[E + e0 + i];
        int pos = atomicAdd(&cur[d >> 6], 1);
        pairs[pos] = (unsigned)s | ((unsigned)(d & 63) << 16);
    }
}

// Pass 4: one workgroup per bucket: 64-bin LDS sort -> coalesced srcs + offs.
__global__ __launch_bounds__(256) void bucket_build(const unsigned* __restrict__ pairs,
                                                    const int* __restrict__ bbase,
                                                    int* __restrict__ offs,
                                                    int* __restrict__ srcs, int N) {
    __shared__ unsigned spk[BCAP];
    __shared__ int stage[BCAP];
    __shared__ int cnt64[64], cur64[64];
    int b = blockIdx.x, t = threadIdx.x;
    int base = bbase[b];
    int cnt = bbase[b + 1] - base; if (cnt > BCAP) cnt = BCAP;
    if (t < 64) cnt64[t] = 0;
    __syncthreads();
    for (int i = t; i < cnt; i += 256) {
        unsigned p = pairs[base + i];
        spk[i] = p;
        atomicAdd(&cnt64[(p >> 16) & 63], 1);
    }
    __syncthreads();
    if (t < 64) {
        int v = cnt64[t], x = v;
#pragma unroll
        for (int o = 1; o < 64; o <<= 1) {
            int y = __shfl_up(x, o);
            if (t >= o) x += y;
        }
        int excl = x - v;
        cur64[t] = excl;
        int node = b * 64 + t;
        if (node < N) offs[node] = base + excl;
    }
    __syncthreads();
    for (int i = t; i < cnt; i += 256) {
        unsigned p = spk[i];
        int pos = atomicAdd(&cur64[(p >> 16) & 63], 1);
        stage[pos] = (int)(p & 0xffffu);
    }
    __syncthreads();
    for (int i = t; i < cnt; i += 256) srcs[base + i] = stage[i];
}

// ---------------- MFMA GEMM 1: y1 = x(fp32) @ W1t, bf16 out, no epilogue ----------------
__global__ void mfma_gemm1(const float* __restrict__ X,
                           const unsigned short* __restrict__ Bt,
                           unsigned short* __restrict__ Y, int Mtiles) {
    int wave = blockIdx.x * 4 + (threadIdx.x >> 6);
    if (wave >= Mtiles) return;
    int lane = threadIdx.x & 63;
    int l15 = lane & 15, quad = lane >> 4;
    const float* arow = X + (long)(wave * 16 + l15) * 96 + quad * 8;
    f32x4 acc[4] = {{0,0,0,0},{0,0,0,0},{0,0,0,0},{0,0,0,0}};
#pragma unroll
    for (int t = 0; t < 3; ++t) {
        float4 p0 = *(const float4*)(arow + t * 32);
        float4 p1 = *(const float4*)(arow + t * 32 + 4);
        union { bf16x8 v; unsigned u[4]; } a;
        a.u[0] = pack2(p0.x, p0.y); a.u[1] = pack2(p0.z, p0.w);
        a.u[2] = pack2(p1.x, p1.y); a.u[3] = pack2(p1.z, p1.w);
#pragma unroll
        for (int nt = 0; nt < 4; ++nt) {
            bf16x8 bfr = *(const bf16x8*)(Bt + (long)(nt * 16 + l15) * 96 + t * 32 + quad * 8);
            acc[nt] = __builtin_amdgcn_mfma_f32_16x16x32_bf16(a.v, bfr, acc[nt], 0, 0, 0);
        }
    }
    int mbase = wave * 16 + quad * 4;  // C/D: row = quad*4 + reg, col = l15
#pragma unroll
    for (int nt = 0; nt < 4; ++nt) {
        int col = nt * 16 + l15;
#pragma unroll
        for (int r = 0; r < 4; ++r)
            Y[(long)(mbase + r) * 64 + col] = f2bf(acc[nt][r]);
    }
}

// ---------------- gather layer 1: h = relu(sum y1[src] + b1), bf16 ----------------
__global__ void gather_relu(const uint4* __restrict__ y1, const int* __restrict__ offs,
                            const int* __restrict__ srcs, const float* __restrict__ bias,
                            uint4* __restrict__ h, int N) {
    int gid = blockIdx.x * blockDim.x + threadIdx.x;
    int n = gid >> 3;
    if (n >= N) return;
    int q = gid & 7;
    int s0 = offs[n], s1 = offs[n + 1];
    float a0 = 0, a1 = 0, a2 = 0, a3 = 0, a4 = 0, a5 = 0, a6 = 0, a7 = 0;
    for (int e = s0; e < s1; ++e) {
        uint4 v = y1[(long)srcs[e] * 8 + q];
        a0 += blo(v.x); a1 += bhi(v.x);
        a2 += blo(v.y); a3 += bhi(v.y);
        a4 += blo(v.z); a5 += bhi(v.z);
        a6 += blo(v.w); a7 += bhi(v.w);
    }
    const float* bq = bias + q * 8;
    a0 = fmaxf(a0 + bq[0], 0.f); a1 = fmaxf(a1 + bq[1], 0.f);
    a2 = fmaxf(a2 + bq[2], 0.f); a3 = fmaxf(a3 + bq[3], 0.f);
    a4 = fmaxf(a4 + bq[4], 0.f); a5 = fmaxf(a5 + bq[5], 0.f);
    a6 = fmaxf(a6 + bq[6], 0.f); a7 = fmaxf(a7 + bq[7], 0.f);
    uint4 o;
    o.x = pack2(a0, a1); o.y = pack2(a2, a3);
    o.z = pack2(a4, a5); o.w = pack2(a6, a7);
    h[(long)n * 8 + q] = o;
}

// ---------------- MFMA GEMM 2: y2 = h @ W2t, bf16 out [N,32] ----------------
__global__ void mfma_gemm2(const unsigned short* __restrict__ A,
                           const unsigned short* __restrict__ Bt,
                           unsigned short* __restrict__ Y, int Mtiles) {
    int wave = blockIdx.x * 4 + (threadIdx.x >> 6);
    if (wave >= Mtiles) return;
    int lane = threadIdx.x & 63;
    int l15 = lane & 15, quad = lane >> 4;
    long arow = (long)(wave * 16 + l15) * 64 + quad * 8;
    f32x4 acc[2] = {{0,0,0,0},{0,0,0,0}};
#pragma unroll
    for (int t = 0; t < 2; ++t) {
        bf16x8 af = *(const bf16x8*)(A + arow + t * 32);
#pragma unroll
        for (int nt = 0; nt < 2; ++nt) {
            bf16x8 bfr = *(const bf16x8*)(Bt + (long)(nt * 16 + l15) * 64 + t * 32 + quad * 8);
            acc[nt] = __builtin_amdgcn_mfma_f32_16x16x32_bf16(af, bfr, acc[nt], 0, 0, 0);
        }
    }
    int mbase = wave * 16 + quad * 4;
#pragma unroll
    for (int nt = 0; nt < 2; ++nt) {
        int col = nt * 16 + l15;
#pragma unroll
        for (int r = 0; r < 4; ++r)
            Y[(long)(mbase + r) * 32 + col] = f2bf(acc[nt][r]);
    }
}

// ---------------- gather layer 2 + fused bias + log_softmax ----------------
// 2 threads per node; each owns 16 cols (2 uint4 chunks); partner shuffle for m,s.
__global__ void gather_lsm(const uint4* __restrict__ y2, const int* __restrict__ offs,
                           const int* __restrict__ srcs, const float* __restrict__ bias,
                           float* __restrict__ out, int N) {
    int gid = blockIdx.x * blockDim.x + threadIdx.x;
    int n = gid >> 1;
    if (n >= N) return;
    int half = gid & 1;
    int s0 = offs[n], s1 = offs[n + 1];
    float a[16];
#pragma unroll
    for (int i = 0; i < 16; ++i) a[i] = 0.f;
    const uint4* base = y2 + half * 2;
    for (int e = s0; e < s1; ++e) {
        long r = (long)srcs[e] * 4;
        uint4 v0 = base[r], v1 = base[r + 1];
        a[0] += blo(v0.x); a[1] += bhi(v0.x);
        a[2] += blo(v0.y); a[3] += bhi(v0.y);
        a[4] += blo(v0.z); a[5] += bhi(v0.z);
        a[6] += blo(v0.w); a[7] += bhi(v0.w);
        a[8]  += blo(v1.x); a[9]  += bhi(v1.x);
        a[10] += blo(v1.y); a[11] += bhi(v1.y);
        a[12] += blo(v1.z); a[13] += bhi(v1.z);
        a[14] += blo(v1.w); a[15] += bhi(v1.w);
    }
    const float* bq = bias + half * 16;
    float m = -1e30f;
#pragma unroll
    for (int i = 0; i < 16; ++i) { a[i] += bq[i]; m = fmaxf(m, a[i]); }
    m = fmaxf(m, __shfl_xor(m, 1));
    float s = 0.f;
#pragma unroll
    for (int i = 0; i < 16; ++i) s += __expf(a[i] - m);
    s += __shfl_xor(s, 1);
    float ls = m + __logf(s);
    float* op = out + (long)n * 32 + half * 16;
#pragma unroll
    for (int i = 0; i < 16; ++i) op[i] = a[i] - ls;
}

extern "C" void kernel_launch(void* const* d_in, const int* in_sizes, int n_in,
                              void* d_out, int out_size, void* d_ws, size_t ws_size,
                              hipStream_t stream) {
    const float* x  = (const float*)d_in[0];      // [N,96]
    const int*   ei = (const int*)d_in[1];        // [2,E] (int64 -> int32 on device)
    const float* W1 = (const float*)d_in[2];      // [96,64]
    const float* b1 = (const float*)d_in[3];      // [64]
    const float* W2 = (const float*)d_in[4];      // [64,32]
    const float* b2 = (const float*)d_in[5];      // [32]
    float* out = (float*)d_out;                   // [N,32]

    const int N = in_sizes[0] / 96;
    const int E = in_sizes[1] / 2;
    const int nb = (N + 63) / 64;                 // 782 coarse buckets
    const int chunk = (E + NBLK - 1) / NBLK;      // 6250 edges per hist/place block

    // ws layout (16B-aligned slabs)
    char* p = (char*)d_ws;
    unsigned short* y1  = (unsigned short*)p;     p += (size_t)N * 64 * 2;   // x@W1 bf16
    unsigned short* hb  = (unsigned short*)p;     p += (size_t)N * 64 * 2;   // relu agg bf16
    unsigned short* y2  = (unsigned short*)p;     p += (size_t)N * 32 * 2;   // h@W2 bf16
    unsigned short* w1t = (unsigned short*)p;     p += 96 * 64 * 2;
    unsigned short* w2t = (unsigned short*)p;     p += 64 * 32 * 2;
    int* offs   = (int*)p;                        p += ((size_t)(N + 1) * 4 + 12) & ~15ull;
    int* counts = (int*)p;                        p += ((size_t)nb * NBLK * 4 + 12) & ~15ull;
    int* bbase  = (int*)p;                        p += ((size_t)(nb + 1) * 4 + 12) & ~15ull;
    unsigned* pairs = (unsigned*)p;               p += (size_t)E * 4;
    int* srcs   = (int*)p;                        p += (size_t)E * 4;

    // weights (one tiny launch)
    cast_weights<<<(96 * 64 + 64 * 32 + 255) / 256, 256, 0, stream>>>(W1, W2, w1t, w2t);

    // CSR build by dst (no global atomics)
    blk_hist<<<NBLK, 256, 0, stream>>>(ei, counts, E, chunk, nb);
    colscan_scan<<<1, 1024, 0, stream>>>(counts, bbase, offs, nb, N, E);
    blk_place<<<NBLK, 256, 0, stream>>>(ei, counts, bbase, pairs, E, chunk, nb);
    bucket_build<<<nb, 256, 0, stream>>>(pairs, bbase, offs, srcs, N);

    const int Mtiles = N / 16;  // 3125

    // Layer 1: project then aggregate (A(xW) = (Ax)W)
    mfma_gemm1<<<(Mtiles + 3) / 4, 256, 0, stream>>>(x, w1t, y1, Mtiles);
    {
        long t = (long)N * 8;
        gather_relu<<<(int)((t + 255) / 256), 256, 0, stream>>>(
            (const uint4*)y1, offs, srcs, b1, (uint4*)hb, N);
    }

    // Layer 2: project then aggregate + fused log_softmax
    mfma_gemm2<<<(Mtiles + 3) / 4, 256, 0, stream>>>(hb, w2t, y2, Mtiles);
    {
        long t = (long)N * 2;
        gather_lsm<<<(int)((t + 255) / 256), 256, 0, stream>>>(
            (const uint4*)y2, offs, srcs, b2, out, N);
    }
}

// Round 8
// 184.630 us; speedup vs baseline: 1.9274x; 1.0718x over previous
//
#include <hip/hip_runtime.h>
#include <hip/hip_bf16.h>

typedef __attribute__((ext_vector_type(8))) short bf16x8;
typedef __attribute__((ext_vector_type(4))) float f32x4;

#define NBLK 128          // blocks for hist/place passes
#define NBINS_PAD 800     // LDS bin array (nb = 782 used)
#define BCAP 2048         // bucket_build LDS capacity (mean 1024, max ~1150)

__device__ inline unsigned short f2bf(float f) {
    unsigned u = __float_as_uint(f);
    return (unsigned short)((u + 0x7fffu + ((u >> 16) & 1u)) >> 16);
}
__device__ inline unsigned pack2(float a, float b) {
    return (unsigned)f2bf(a) | ((unsigned)f2bf(b) << 16);
}
__device__ inline float blo(unsigned u) { return __uint_as_float(u << 16); }
__device__ inline float bhi(unsigned u) { return __uint_as_float(u & 0xffff0000u); }

__device__ inline void acc8(float* a, uint4 v) {
    a[0] += blo(v.x); a[1] += bhi(v.x);
    a[2] += blo(v.y); a[3] += bhi(v.y);
    a[4] += blo(v.z); a[5] += bhi(v.z);
    a[6] += blo(v.w); a[7] += bhi(v.w);
}

// ---------------- Pass 1: per-block LDS hist (+ weights cast in last block) ----------------
// counts stored TRANSPOSED: counts[j*NBLK + b].
__global__ __launch_bounds__(256) void blk_hist_cast(const int* __restrict__ ei,
                                                     int* __restrict__ counts,
                                                     int E, int chunk, int nb,
                                                     const float* __restrict__ W1,
                                                     const float* __restrict__ W2,
                                                     unsigned short* __restrict__ w1t,
                                                     unsigned short* __restrict__ w2t) {
    int b = blockIdx.x, t = threadIdx.x;
    if (b == NBLK) {  // weights block: w1t[n][k]=W1[k][n], w2t[n][k]=W2[k][n]
        for (int idx = t; idx < 96 * 64; idx += 256) {
            int n = idx / 96, k = idx - n * 96;
            w1t[idx] = f2bf(W1[k * 64 + n]);
        }
        for (int idx = t; idx < 64 * 32; idx += 256) {
            int n = idx / 64, k = idx - n * 64;
            w2t[idx] = f2bf(W2[k * 32 + n]);
        }
        return;
    }
    __shared__ int hist[NBINS_PAD];
    for (int i = t; i < NBINS_PAD; i += 256) hist[i] = 0;
    __syncthreads();
    int e0 = b * chunk;
    int n = E - e0; if (n > chunk) n = chunk; if (n < 0) n = 0;
    for (int i = t; i < n; i += 256) atomicAdd(&hist[ei[E + e0 + i] >> 6], 1);
    __syncthreads();
    for (int j = t; j < nb; j += 256) counts[j * NBLK + b] = hist[j];
}

// ---------------- Pass 2: fused cross-block + bucket scan ----------------
__global__ __launch_bounds__(1024) void colscan_scan(int* __restrict__ counts,
                                                     int* __restrict__ bbase,
                                                     int* __restrict__ offs,
                                                     int nb, int N, int E) {
    __shared__ int lds[1024];
    int j = threadIdx.x;
    int run = 0;
    if (j < nb) {
        int* row = counts + (size_t)j * NBLK;
#pragma unroll 4
        for (int b = 0; b < NBLK; ++b) { int c = row[b]; row[b] = run; run += c; }
    }
    lds[j] = (j < nb) ? run : 0;
    __syncthreads();
    for (int off = 1; off < 1024; off <<= 1) {
        int t = (j >= off) ? lds[j - off] : 0;
        __syncthreads();
        lds[j] += t;
        __syncthreads();
    }
    if (j < nb) bbase[j] = lds[j] - run;
    if (j == 0) { bbase[nb] = E; offs[N] = E; }
}

// ---------------- Pass 3: place packed pairs (LDS atomics only) ----------------
__global__ __launch_bounds__(256) void blk_place(const int* __restrict__ ei,
                                                 const int* __restrict__ counts,
                                                 const int* __restrict__ bbase,
                                                 unsigned* __restrict__ pairs,
                                                 int E, int chunk, int nb) {
    __shared__ int cur[NBINS_PAD];
    int b = blockIdx.x, t = threadIdx.x;
    for (int j = t; j < nb; j += 256) cur[j] = bbase[j] + counts[j * NBLK + b];
    __syncthreads();
    int e0 = b * chunk;
    int n = E - e0; if (n > chunk) n = chunk; if (n < 0) n = 0;
    for (int i = t; i < n; i += 256) {
        int s = ei[e0 + i], d = ei[E + e0 + i];
        int pos = atomicAdd(&cur[d >> 6], 1);
        pairs[pos] = (unsigned)s | ((unsigned)(d & 63) << 16);
    }
}

// ---------------- Pass 4: per-bucket 64-bin LDS sort -> srcs + offs ----------------
__global__ __launch_bounds__(256) void bucket_build(const unsigned* __restrict__ pairs,
                                                    const int* __restrict__ bbase,
                                                    int* __restrict__ offs,
                                                    int* __restrict__ srcs, int N) {
    __shared__ unsigned spk[BCAP];
    __shared__ int stage[BCAP];
    __shared__ int cnt64[64], cur64[64];
    int b = blockIdx.x, t = threadIdx.x;
    int base = bbase[b];
    int cnt = bbase[b + 1] - base; if (cnt > BCAP) cnt = BCAP;
    if (t < 64) cnt64[t] = 0;
    __syncthreads();
    for (int i = t; i < cnt; i += 256) {
        unsigned p = pairs[base + i];
        spk[i] = p;
        atomicAdd(&cnt64[(p >> 16) & 63], 1);
    }
    __syncthreads();
    if (t < 64) {
        int v = cnt64[t], x = v;
#pragma unroll
        for (int o = 1; o < 64; o <<= 1) {
            int y = __shfl_up(x, o);
            if (t >= o) x += y;
        }
        int excl = x - v;
        cur64[t] = excl;
        int node = b * 64 + t;
        if (node < N) offs[node] = base + excl;
    }
    __syncthreads();
    for (int i = t; i < cnt; i += 256) {
        unsigned p = spk[i];
        int pos = atomicAdd(&cur64[(p >> 16) & 63], 1);
        stage[pos] = (int)(p & 0xffffu);
    }
    __syncthreads();
    for (int i = t; i < cnt; i += 256) srcs[base + i] = stage[i];
}

// ---------------- MFMA GEMM 1: y1 = x(fp32) @ W1t, bf16 out ----------------
__global__ void mfma_gemm1(const float* __restrict__ X,
                           const unsigned short* __restrict__ Bt,
                           unsigned short* __restrict__ Y, int Mtiles) {
    int wave = blockIdx.x * 4 + (threadIdx.x >> 6);
    if (wave >= Mtiles) return;
    int lane = threadIdx.x & 63;
    int l15 = lane & 15, quad = lane >> 4;
    const float* arow = X + (long)(wave * 16 + l15) * 96 + quad * 8;
    f32x4 acc[4] = {{0,0,0,0},{0,0,0,0},{0,0,0,0},{0,0,0,0}};
#pragma unroll
    for (int t = 0; t < 3; ++t) {
        float4 p0 = *(const float4*)(arow + t * 32);
        float4 p1 = *(const float4*)(arow + t * 32 + 4);
        union { bf16x8 v; unsigned u[4]; } a;
        a.u[0] = pack2(p0.x, p0.y); a.u[1] = pack2(p0.z, p0.w);
        a.u[2] = pack2(p1.x, p1.y); a.u[3] = pack2(p1.z, p1.w);
#pragma unroll
        for (int nt = 0; nt < 4; ++nt) {
            bf16x8 bfr = *(const bf16x8*)(Bt + (long)(nt * 16 + l15) * 96 + t * 32 + quad * 8);
            acc[nt] = __builtin_amdgcn_mfma_f32_16x16x32_bf16(a.v, bfr, acc[nt], 0, 0, 0);
        }
    }
    int mbase = wave * 16 + quad * 4;  // C/D: row = quad*4 + reg, col = l15
#pragma unroll
    for (int nt = 0; nt < 4; ++nt) {
        int col = nt * 16 + l15;
#pragma unroll
        for (int r = 0; r < 4; ++r)
            Y[(long)(mbase + r) * 64 + col] = f2bf(acc[nt][r]);
    }
}

// ---------------- gather layer 1: h = relu(sum y1[src] + b1), bf16 ----------------
// 4 threads/node, 16 feats (2 uint4) each; edge loop unrolled x4 (8 loads in flight).
__global__ void gather_relu(const uint4* __restrict__ y1, const int* __restrict__ offs,
                            const int* __restrict__ srcs, const float* __restrict__ bias,
                            uint4* __restrict__ h, int N) {
    int gid = blockIdx.x * blockDim.x + threadIdx.x;
    int n = gid >> 2;
    if (n >= N) return;
    int q = gid & 3;
    int s0 = offs[n], s1 = offs[n + 1];
    float a[16];
#pragma unroll
    for (int i = 0; i < 16; ++i) a[i] = 0.f;
    const uint4* base = y1 + q * 2;   // row stride 8 uint4
    int e = s0;
    for (; e + 4 <= s1; e += 4) {
        long r0 = (long)srcs[e] * 8, r1 = (long)srcs[e + 1] * 8;
        long r2 = (long)srcs[e + 2] * 8, r3 = (long)srcs[e + 3] * 8;
        uint4 u0a = base[r0], u0b = base[r0 + 1];
        uint4 u1a = base[r1], u1b = base[r1 + 1];
        uint4 u2a = base[r2], u2b = base[r2 + 1];
        uint4 u3a = base[r3], u3b = base[r3 + 1];
        acc8(a, u0a); acc8(a + 8, u0b);
        acc8(a, u1a); acc8(a + 8, u1b);
        acc8(a, u2a); acc8(a + 8, u2b);
        acc8(a, u3a); acc8(a + 8, u3b);
    }
    for (; e < s1; ++e) {
        long r = (long)srcs[e] * 8;
        uint4 ua = base[r], ub = base[r + 1];
        acc8(a, ua); acc8(a + 8, ub);
    }
    const float* bq = bias + q * 16;
#pragma unroll
    for (int i = 0; i < 16; ++i) a[i] = fmaxf(a[i] + bq[i], 0.f);
    uint4 o0, o1;
    o0.x = pack2(a[0], a[1]);  o0.y = pack2(a[2], a[3]);
    o0.z = pack2(a[4], a[5]);  o0.w = pack2(a[6], a[7]);
    o1.x = pack2(a[8], a[9]);  o1.y = pack2(a[10], a[11]);
    o1.z = pack2(a[12], a[13]); o1.w = pack2(a[14], a[15]);
    h[(long)n * 8 + q * 2] = o0;
    h[(long)n * 8 + q * 2 + 1] = o1;
}

// ---------------- MFMA GEMM 2: y2 = h @ W2t, bf16 out [N,32] ----------------
__global__ void mfma_gemm2(const unsigned short* __restrict__ A,
                           const unsigned short* __restrict__ Bt,
                           unsigned short* __restrict__ Y, int Mtiles) {
    int wave = blockIdx.x * 4 + (threadIdx.x >> 6);
    if (wave >= Mtiles) return;
    int lane = threadIdx.x & 63;
    int l15 = lane & 15, quad = lane >> 4;
    long arow = (long)(wave * 16 + l15) * 64 + quad * 8;
    f32x4 acc[2] = {{0,0,0,0},{0,0,0,0}};
#pragma unroll
    for (int t = 0; t < 2; ++t) {
        bf16x8 af = *(const bf16x8*)(A + arow + t * 32);
#pragma unroll
        for (int nt = 0; nt < 2; ++nt) {
            bf16x8 bfr = *(const bf16x8*)(Bt + (long)(nt * 16 + l15) * 64 + t * 32 + quad * 8);
            acc[nt] = __builtin_amdgcn_mfma_f32_16x16x32_bf16(af, bfr, acc[nt], 0, 0, 0);
        }
    }
    int mbase = wave * 16 + quad * 4;
#pragma unroll
    for (int nt = 0; nt < 2; ++nt) {
        int col = nt * 16 + l15;
#pragma unroll
        for (int r = 0; r < 4; ++r)
            Y[(long)(mbase + r) * 32 + col] = f2bf(acc[nt][r]);
    }
}

// ---------------- gather layer 2 + fused bias + log_softmax ----------------
// 2 threads/node, 16 cols (2 uint4) each; edge loop unrolled x4; partner shuffle.
__global__ void gather_lsm(const uint4* __restrict__ y2, const int* __restrict__ offs,
                           const int* __restrict__ srcs, const float* __restrict__ bias,
                           float* __restrict__ out, int N) {
    int gid = blockIdx.x * blockDim.x + threadIdx.x;
    int n = gid >> 1;
    if (n >= N) return;
    int half = gid & 1;
    int s0 = offs[n], s1 = offs[n + 1];
    float a[16];
#pragma unroll
    for (int i = 0; i < 16; ++i) a[i] = 0.f;
    const uint4* base = y2 + half * 2;   // row stride 4 uint4
    int e = s0;
    for (; e + 4 <= s1; e += 4) {
        long r0 = (long)srcs[e] * 4, r1 = (long)srcs[e + 1] * 4;
        long r2 = (long)srcs[e + 2] * 4, r3 = (long)srcs[e + 3] * 4;
        uint4 u0a = base[r0], u0b = base[r0 + 1];
        uint4 u1a = base[r1], u1b = base[r1 + 1];
        uint4 u2a = base[r2], u2b = base[r2 + 1];
        uint4 u3a = base[r3], u3b = base[r3 + 1];
        acc8(a, u0a); acc8(a + 8, u0b);
        acc8(a, u1a); acc8(a + 8, u1b);
        acc8(a, u2a); acc8(a + 8, u2b);
        acc8(a, u3a); acc8(a + 8, u3b);
    }
    for (; e < s1; ++e) {
        long r = (long)srcs[e] * 4;
        uint4 ua = base[r], ub = base[r + 1];
        acc8(a, ua); acc8(a + 8, ub);
    }
    const float* bq = bias + half * 16;
    float m = -1e30f;
#pragma unroll
    for (int i = 0; i < 16; ++i) { a[i] += bq[i]; m = fmaxf(m, a[i]); }
    m = fmaxf(m, __shfl_xor(m, 1));
    float s = 0.f;
#pragma unroll
    for (int i = 0; i < 16; ++i) s += __expf(a[i] - m);
    s += __shfl_xor(s, 1);
    float ls = m + __logf(s);
    float* op = out + (long)n * 32 + half * 16;
#pragma unroll
    for (int i = 0; i < 16; ++i) op[i] = a[i] - ls;
}

extern "C" void kernel_launch(void* const* d_in, const int* in_sizes, int n_in,
                              void* d_out, int out_size, void* d_ws, size_t ws_size,
                              hipStream_t stream) {
    const float* x  = (const float*)d_in[0];      // [N,96]
    const int*   ei = (const int*)d_in[1];        // [2,E] (int64 -> int32 on device)
    const float* W1 = (const float*)d_in[2];      // [96,64]
    const float* b1 = (const float*)d_in[3];      // [64]
    const float* W2 = (const float*)d_in[4];      // [64,32]
    const float* b2 = (const float*)d_in[5];      // [32]
    float* out = (float*)d_out;                   // [N,32]

    const int N = in_sizes[0] / 96;
    const int E = in_sizes[1] / 2;
    const int nb = (N + 63) / 64;                 // 782 coarse buckets
    const int chunk = (E + NBLK - 1) / NBLK;      // 6250 edges per hist/place block

    // ws layout (16B-aligned slabs)
    char* p = (char*)d_ws;
    unsigned short* y1  = (unsigned short*)p;     p += (size_t)N * 64 * 2;   // x@W1 bf16
    unsigned short* hb  = (unsigned short*)p;     p += (size_t)N * 64 * 2;   // relu agg bf16
    unsigned short* y2  = (unsigned short*)p;     p += (size_t)N * 32 * 2;   // h@W2 bf16
    unsigned short* w1t = (unsigned short*)p;     p += 96 * 64 * 2;
    unsigned short* w2t = (unsigned short*)p;     p += 64 * 32 * 2;
    int* offs   = (int*)p;                        p += ((size_t)(N + 1) * 4 + 12) & ~15ull;
    int* counts = (int*)p;                        p += ((size_t)nb * NBLK * 4 + 12) & ~15ull;
    int* bbase  = (int*)p;                        p += ((size_t)(nb + 1) * 4 + 12) & ~15ull;
    unsigned* pairs = (unsigned*)p;               p += (size_t)E * 4;
    int* srcs   = (int*)p;                        p += (size_t)E * 4;

    // CSR build by dst (no global atomics); last block casts weights
    blk_hist_cast<<<NBLK + 1, 256, 0, stream>>>(ei, counts, E, chunk, nb, W1, W2, w1t, w2t);
    colscan_scan<<<1, 1024, 0, stream>>>(counts, bbase, offs, nb, N, E);
    blk_place<<<NBLK, 256, 0, stream>>>(ei, counts, bbase, pairs, E, chunk, nb);
    bucket_build<<<nb, 256, 0, stream>>>(pairs, bbase, offs, srcs, N);

    const int Mtiles = N / 16;  // 3125

    // Layer 1: project then aggregate (A(xW) = (Ax)W)
    mfma_gemm1<<<(Mtiles + 3) / 4, 256, 0, stream>>>(x, w1t, y1, Mtiles);
    {
        long t = (long)N * 4;
        gather_relu<<<(int)((t + 255) / 256), 256, 0, stream>>>(
            (const uint4*)y1, offs, srcs, b1, (uint4*)hb, N);
    }

    // Layer 2: project then aggregate + fused log_softmax
    mfma_gemm2<<<(Mtiles + 3) / 4, 256, 0, stream>>>(hb, w2t, y2, Mtiles);
    {
        long t = (long)N * 2;
        gather_lsm<<<(int)((t + 255) / 256), 256, 0, stream>>>(
            (const uint4*)y2, offs, srcs, b2, out, N);
    }
}

// Round 9
// 157.276 us; speedup vs baseline: 2.2626x; 1.1739x over previous
//
#include <hip/hip_runtime.h>
#include <hip/hip_bf16.h>

typedef __attribute__((ext_vector_type(8))) short bf16x8;
typedef __attribute__((ext_vector_type(4))) float f32x4;

#define NBLK 128          // blocks for hist/place passes
#define NBINS_PAD 800     // LDS bin array (nb = 782 used)
#define BCAP 2048         // bucket_build LDS capacity (mean 1024, max ~1170)
#define W1LD 104          // LDS leading dim for 96-wide W1 rows (bank-conflict pad)

__device__ inline unsigned short f2bf(float f) {
    unsigned u = __float_as_uint(f);
    return (unsigned short)((u + 0x7fffu + ((u >> 16) & 1u)) >> 16);
}
__device__ inline unsigned pack2(float a, float b) {
    return (unsigned)f2bf(a) | ((unsigned)f2bf(b) << 16);
}
__device__ inline float blo(unsigned u) { return __uint_as_float(u << 16); }
__device__ inline float bhi(unsigned u) { return __uint_as_float(u & 0xffff0000u); }

__device__ inline void acc8(float* a, uint4 v) {
    a[0] += blo(v.x); a[1] += bhi(v.x);
    a[2] += blo(v.y); a[3] += bhi(v.y);
    a[4] += blo(v.z); a[5] += bhi(v.z);
    a[6] += blo(v.w); a[7] += bhi(v.w);
}

// ---------------- K1: hist (b<NBLK) + w2 cast (b==NBLK) + gemm1 (b>NBLK) ----------------
// counts stored TRANSPOSED: counts[j*NBLK + b].
// gemm1: y1 = x(fp32) @ W1 -> split slabs y1a (cols 0..31), y1b (cols 32..63), bf16.
// W1 converted to LDS per gemm1 block (no cross-block dependency).
__global__ __launch_bounds__(256) void fused_hist_gemm1(
        const int* __restrict__ ei, int* __restrict__ counts, int E, int chunk, int nb,
        const float* __restrict__ W1, const float* __restrict__ W2,
        unsigned short* __restrict__ w2t,
        const float* __restrict__ X,
        unsigned short* __restrict__ y1a, unsigned short* __restrict__ y1b, int Mtiles) {
    __shared__ int hist[NBINS_PAD];
    __shared__ unsigned short w1l[64 * W1LD];
    int b = blockIdx.x, t = threadIdx.x;
    if (b < NBLK) {
        for (int i = t; i < NBINS_PAD; i += 256) hist[i] = 0;
        __syncthreads();
        int e0 = b * chunk;
        int n = E - e0; if (n > chunk) n = chunk; if (n < 0) n = 0;
        for (int i = t; i < n; i += 256) atomicAdd(&hist[ei[E + e0 + i] >> 6], 1);
        __syncthreads();
        for (int j = t; j < nb; j += 256) counts[j * NBLK + b] = hist[j];
        return;
    }
    if (b == NBLK) {  // w2t[n][k] = bf16(W2[k][n])  (32x64)
        for (int idx = t; idx < 64 * 32; idx += 256) {
            int n = idx / 64, k = idx - n * 64;
            w2t[idx] = f2bf(W2[k * 32 + n]);
        }
        return;
    }
    // --- gemm1 block ---
    for (int idx = t; idx < 96 * 64; idx += 256) {
        int n = idx / 96, k = idx - n * 96;
        w1l[n * W1LD + k] = f2bf(W1[k * 64 + n]);
    }
    __syncthreads();
    int wave = (b - NBLK - 1) * 4 + (t >> 6);
    if (wave >= Mtiles) return;
    int lane = t & 63;
    int l15 = lane & 15, quad = lane >> 4;
    const float* arow = X + (long)(wave * 16 + l15) * 96 + quad * 8;
    f32x4 acc[4] = {{0,0,0,0},{0,0,0,0},{0,0,0,0},{0,0,0,0}};
#pragma unroll
    for (int tt = 0; tt < 3; ++tt) {
        float4 p0 = *(const float4*)(arow + tt * 32);
        float4 p1 = *(const float4*)(arow + tt * 32 + 4);
        union { bf16x8 v; unsigned u[4]; } a;
        a.u[0] = pack2(p0.x, p0.y); a.u[1] = pack2(p0.z, p0.w);
        a.u[2] = pack2(p1.x, p1.y); a.u[3] = pack2(p1.z, p1.w);
#pragma unroll
        for (int nt = 0; nt < 4; ++nt) {
            bf16x8 bfr = *(const bf16x8*)(w1l + (nt * 16 + l15) * W1LD + tt * 32 + quad * 8);
            acc[nt] = __builtin_amdgcn_mfma_f32_16x16x32_bf16(a.v, bfr, acc[nt], 0, 0, 0);
        }
    }
    int mbase = wave * 16 + quad * 4;  // C/D: row = quad*4 + reg, col = l15
#pragma unroll
    for (int nt = 0; nt < 4; ++nt) {
        int col = nt * 16 + l15;
        unsigned short* slab = (col < 32) ? y1a : y1b;
        int colh = col & 31;
#pragma unroll
        for (int r = 0; r < 4; ++r)
            slab[(long)(mbase + r) * 32 + colh] = f2bf(acc[nt][r]);
    }
}

// ---------------- K2a: wave-per-row exclusive scan of counts rows ----------------
__global__ __launch_bounds__(256) void rowscan(int* __restrict__ counts,
                                               int* __restrict__ btot, int nb) {
    int w = (blockIdx.x * 256 + threadIdx.x) >> 6;
    int lane = threadIdx.x & 63;
    if (w >= nb) return;
    int* row = counts + (size_t)w * NBLK;
    int c0 = row[lane * 2], c1 = row[lane * 2 + 1];
    int s = c0 + c1;
#pragma unroll
    for (int o = 1; o < 64; o <<= 1) {
        int tt = __shfl_up(s, o);
        if (lane >= o) s += tt;
    }
    int excl = s - (c0 + c1);
    row[lane * 2] = excl;
    row[lane * 2 + 1] = excl + c0;
    if (lane == 63) btot[w] = s;
}

// ---------------- K2b: single-block scan of bucket totals ----------------
__global__ __launch_bounds__(1024) void bucketscan(const int* __restrict__ btot,
                                                   int* __restrict__ bbase,
                                                   int* __restrict__ offs,
                                                   int nb, int N, int E) {
    __shared__ int lds[1024];
    int j = threadIdx.x;
    int v = (j < nb) ? btot[j] : 0;
    lds[j] = v;
    __syncthreads();
    for (int off = 1; off < 1024; off <<= 1) {
        int tt = (j >= off) ? lds[j - off] : 0;
        __syncthreads();
        lds[j] += tt;
        __syncthreads();
    }
    if (j < nb) bbase[j] = lds[j] - v;
    if (j == 0) { bbase[nb] = E; offs[N] = E; }
}

// ---------------- K3: place packed pairs (LDS atomics only) ----------------
__global__ __launch_bounds__(256) void blk_place(const int* __restrict__ ei,
                                                 const int* __restrict__ counts,
                                                 const int* __restrict__ bbase,
                                                 unsigned* __restrict__ pairs,
                                                 int E, int chunk, int nb) {
    __shared__ int cur[NBINS_PAD];
    int b = blockIdx.x, t = threadIdx.x;
    for (int j = t; j < nb; j += 256) cur[j] = bbase[j] + counts[j * NBLK + b];
    __syncthreads();
    int e0 = b * chunk;
    int n = E - e0; if (n > chunk) n = chunk; if (n < 0) n = 0;
    for (int i = t; i < n; i += 256) {
        int s = ei[e0 + i], d = ei[E + e0 + i];
        int pos = atomicAdd(&cur[d >> 6], 1);
        pairs[pos] = (unsigned)s | ((unsigned)(d & 63) << 16);
    }
}

// ---------------- K4: per-bucket 64-bin LDS sort -> srcs + offs ----------------
__global__ __launch_bounds__(256) void bucket_build(const unsigned* __restrict__ pairs,
                                                    const int* __restrict__ bbase,
                                                    int* __restrict__ offs,
                                                    int* __restrict__ srcs, int N) {
    __shared__ unsigned spk[BCAP];
    __shared__ int stage[BCAP];
    __shared__ int cnt64[64], cur64[64];
    int b = blockIdx.x, t = threadIdx.x;
    int base = bbase[b];
    int cnt = bbase[b + 1] - base; if (cnt > BCAP) cnt = BCAP;
    if (t < 64) cnt64[t] = 0;
    __syncthreads();
    for (int i = t; i < cnt; i += 256) {
        unsigned p = pairs[base + i];
        spk[i] = p;
        atomicAdd(&cnt64[(p >> 16) & 63], 1);
    }
    __syncthreads();
    if (t < 64) {
        int v = cnt64[t], x = v;
#pragma unroll
        for (int o = 1; o < 64; o <<= 1) {
            int y = __shfl_up(x, o);
            if (t >= o) x += y;
        }
        int excl = x - v;
        cur64[t] = excl;
        int node = b * 64 + t;
        if (node < N) offs[node] = base + excl;
    }
    __syncthreads();
    for (int i = t; i < cnt; i += 256) {
        unsigned p = spk[i];
        int pos = atomicAdd(&cur64[(p >> 16) & 63], 1);
        stage[pos] = (int)(p & 0xffffu);
    }
    __syncthreads();
    for (int i = t; i < cnt; i += 256) srcs[base + i] = stage[i];
}

// ---------------- K5/K6: half-feature gather + bias + relu (L2-resident slab) ----------------
// 2 threads/node; each sums 16 feats (2 uint4) of the 32-feat half; edge loop x4 unroll.
__global__ void gather_relu_half(const uint4* __restrict__ y1h, const int* __restrict__ offs,
                                 const int* __restrict__ srcs, const float* __restrict__ biash,
                                 uint4* __restrict__ hh, int N) {
    int gid = blockIdx.x * blockDim.x + threadIdx.x;
    int n = gid >> 1;
    if (n >= N) return;
    int q = gid & 1;
    int s0 = offs[n], s1 = offs[n + 1];
    float a[16];
#pragma unroll
    for (int i = 0; i < 16; ++i) a[i] = 0.f;
    const uint4* base = y1h + q * 2;   // row stride 4 uint4 (32 bf16)
    int e = s0;
    for (; e + 4 <= s1; e += 4) {
        long r0 = (long)srcs[e] * 4, r1 = (long)srcs[e + 1] * 4;
        long r2 = (long)srcs[e + 2] * 4, r3 = (long)srcs[e + 3] * 4;
        uint4 u0a = base[r0], u0b = base[r0 + 1];
        uint4 u1a = base[r1], u1b = base[r1 + 1];
        uint4 u2a = base[r2], u2b = base[r2 + 1];
        uint4 u3a = base[r3], u3b = base[r3 + 1];
        acc8(a, u0a); acc8(a + 8, u0b);
        acc8(a, u1a); acc8(a + 8, u1b);
        acc8(a, u2a); acc8(a + 8, u2b);
        acc8(a, u3a); acc8(a + 8, u3b);
    }
    for (; e < s1; ++e) {
        long r = (long)srcs[e] * 4;
        uint4 ua = base[r], ub = base[r + 1];
        acc8(a, ua); acc8(a + 8, ub);
    }
    const float* bq = biash + q * 16;
#pragma unroll
    for (int i = 0; i < 16; ++i) a[i] = fmaxf(a[i] + bq[i], 0.f);
    uint4 o0, o1;
    o0.x = pack2(a[0], a[1]);   o0.y = pack2(a[2], a[3]);
    o0.z = pack2(a[4], a[5]);   o0.w = pack2(a[6], a[7]);
    o1.x = pack2(a[8], a[9]);   o1.y = pack2(a[10], a[11]);
    o1.z = pack2(a[12], a[13]); o1.w = pack2(a[14], a[15]);
    hh[(long)n * 4 + q * 2] = o0;
    hh[(long)n * 4 + q * 2 + 1] = o1;
}

// ---------------- K7: y2 = h @ W2t, bf16 out [N,32]; h in split slabs ----------------
__global__ void mfma_gemm2(const unsigned short* __restrict__ hA,
                           const unsigned short* __restrict__ hB,
                           const unsigned short* __restrict__ Bt,
                           unsigned short* __restrict__ Y, int Mtiles) {
    int wave = blockIdx.x * 4 + (threadIdx.x >> 6);
    if (wave >= Mtiles) return;
    int lane = threadIdx.x & 63;
    int l15 = lane & 15, quad = lane >> 4;
    long arow = (long)(wave * 16 + l15) * 32 + quad * 8;
    f32x4 acc[2] = {{0,0,0,0},{0,0,0,0}};
#pragma unroll
    for (int t = 0; t < 2; ++t) {
        const unsigned short* hs = t ? hB : hA;
        bf16x8 af = *(const bf16x8*)(hs + arow);
#pragma unroll
        for (int nt = 0; nt < 2; ++nt) {
            bf16x8 bfr = *(const bf16x8*)(Bt + (long)(nt * 16 + l15) * 64 + t * 32 + quad * 8);
            acc[nt] = __builtin_amdgcn_mfma_f32_16x16x32_bf16(af, bfr, acc[nt], 0, 0, 0);
        }
    }
    int mbase = wave * 16 + quad * 4;
#pragma unroll
    for (int nt = 0; nt < 2; ++nt) {
        int col = nt * 16 + l15;
#pragma unroll
        for (int r = 0; r < 4; ++r)
            Y[(long)(mbase + r) * 32 + col] = f2bf(acc[nt][r]);
    }
}

// ---------------- K8: gather layer 2 + fused bias + log_softmax ----------------
__global__ void gather_lsm(const uint4* __restrict__ y2, const int* __restrict__ offs,
                           const int* __restrict__ srcs, const float* __restrict__ bias,
                           float* __restrict__ out, int N) {
    int gid = blockIdx.x * blockDim.x + threadIdx.x;
    int n = gid >> 1;
    if (n >= N) return;
    int half = gid & 1;
    int s0 = offs[n], s1 = offs[n + 1];
    float a[16];
#pragma unroll
    for (int i = 0; i < 16; ++i) a[i] = 0.f;
    const uint4* base = y2 + half * 2;   // row stride 4 uint4
    int e = s0;
    for (; e + 4 <= s1; e += 4) {
        long r0 = (long)srcs[e] * 4, r1 = (long)srcs[e + 1] * 4;
        long r2 = (long)srcs[e + 2] * 4, r3 = (long)srcs[e + 3] * 4;
        uint4 u0a = base[r0], u0b = base[r0 + 1];
        uint4 u1a = base[r1], u1b = base[r1 + 1];
        uint4 u2a = base[r2], u2b = base[r2 + 1];
        uint4 u3a = base[r3], u3b = base[r3 + 1];
        acc8(a, u0a); acc8(a + 8, u0b);
        acc8(a, u1a); acc8(a + 8, u1b);
        acc8(a, u2a); acc8(a + 8, u2b);
        acc8(a, u3a); acc8(a + 8, u3b);
    }
    for (; e < s1; ++e) {
        long r = (long)srcs[e] * 4;
        uint4 ua = base[r], ub = base[r + 1];
        acc8(a, ua); acc8(a + 8, ub);
    }
    const float* bq = bias + half * 16;
    float m = -1e30f;
#pragma unroll
    for (int i = 0; i < 16; ++i) { a[i] += bq[i]; m = fmaxf(m, a[i]); }
    m = fmaxf(m, __shfl_xor(m, 1));
    float s = 0.f;
#pragma unroll
    for (int i = 0; i < 16; ++i) s += __expf(a[i] - m);
    s += __shfl_xor(s, 1);
    float ls = m + __logf(s);
    float* op = out + (long)n * 32 + half * 16;
#pragma unroll
    for (int i = 0; i < 16; ++i) op[i] = a[i] - ls;
}

extern "C" void kernel_launch(void* const* d_in, const int* in_sizes, int n_in,
                              void* d_out, int out_size, void* d_ws, size_t ws_size,
                              hipStream_t stream) {
    const float* x  = (const float*)d_in[0];      // [N,96]
    const int*   ei = (const int*)d_in[1];        // [2,E] (int64 -> int32 on device)
    const float* W1 = (const float*)d_in[2];      // [96,64]
    const float* b1 = (const float*)d_in[3];      // [64]
    const float* W2 = (const float*)d_in[4];      // [64,32]
    const float* b2 = (const float*)d_in[5];      // [32]
    float* out = (float*)d_out;                   // [N,32]

    const int N = in_sizes[0] / 96;
    const int E = in_sizes[1] / 2;
    const int nb = (N + 63) / 64;                 // 782 coarse buckets
    const int chunk = (E + NBLK - 1) / NBLK;      // 6250 edges per hist/place block

    // ws layout (16B-aligned slabs)
    char* p = (char*)d_ws;
    unsigned short* y1a = (unsigned short*)p;     p += (size_t)N * 32 * 2;   // x@W1 cols 0..31
    unsigned short* y1b = (unsigned short*)p;     p += (size_t)N * 32 * 2;   // x@W1 cols 32..63
    unsigned short* hA  = (unsigned short*)p;     p += (size_t)N * 32 * 2;   // h cols 0..31
    unsigned short* hB  = (unsigned short*)p;     p += (size_t)N * 32 * 2;   // h cols 32..63
    unsigned short* y2  = (unsigned short*)p;     p += (size_t)N * 32 * 2;   // h@W2
    unsigned short* w2t = (unsigned short*)p;     p += 64 * 32 * 2;
    int* offs   = (int*)p;                        p += ((size_t)(N + 1) * 4 + 12) & ~15ull;
    int* counts = (int*)p;                        p += ((size_t)nb * NBLK * 4 + 12) & ~15ull;
    int* btot   = (int*)p;                        p += ((size_t)nb * 4 + 12) & ~15ull;
    int* bbase  = (int*)p;                        p += ((size_t)(nb + 1) * 4 + 12) & ~15ull;
    unsigned* pairs = (unsigned*)p;               p += (size_t)E * 4;
    int* srcs   = (int*)p;                        p += (size_t)E * 4;

    const int Mtiles = N / 16;  // 3125
    const int g1blocks = (Mtiles + 3) / 4;  // 782

    // K1: hist + w2 cast + gemm1 (independent work, one launch)
    fused_hist_gemm1<<<NBLK + 1 + g1blocks, 256, 0, stream>>>(
        ei, counts, E, chunk, nb, W1, W2, w2t, x, y1a, y1b, Mtiles);
    // K2: scans
    rowscan<<<(nb * 64 + 255) / 256, 256, 0, stream>>>(counts, btot, nb);
    bucketscan<<<1, 1024, 0, stream>>>(btot, bbase, offs, nb, N, E);
    // K3/K4: place + per-bucket sort
    blk_place<<<NBLK, 256, 0, stream>>>(ei, counts, bbase, pairs, E, chunk, nb);
    bucket_build<<<nb, 256, 0, stream>>>(pairs, bbase, offs, srcs, N);

    // K5/K6: layer-1 aggregation, one L2-resident half-slab per pass
    {
        int grid = (N * 2 + 255) / 256;
        gather_relu_half<<<grid, 256, 0, stream>>>(
            (const uint4*)y1a, offs, srcs, b1, (uint4*)hA, N);
        gather_relu_half<<<grid, 256, 0, stream>>>(
            (const uint4*)y1b, offs, srcs, b1 + 32, (uint4*)hB, N);
    }

    // K7: layer-2 projection
    mfma_gemm2<<<g1blocks, 256, 0, stream>>>(hA, hB, w2t, y2, Mtiles);

    // K8: layer-2 aggregation + fused log_softmax
    gather_lsm<<<(N * 2 + 255) / 256, 256, 0, stream>>>(
        (const uint4*)y2, offs, srcs, b2, out, N);
}